// Round 4
// baseline (1166.756 us; speedup 1.0000x reference)
//
#include <hip/hip_runtime.h>

// Packed-sequence GRU decoder + fused log_softmax head, MFMA formulation, v4.
// T=512, B=1024, V=64, H=100.
//
// 64 blocks x 512 threads (8 waves); block owns 16 batch rows (one MFMA M-tile).
// Waves 0..6: gate tile w (16 gate cols x 3 sections r/z/n) via
//   mfma_f32_16x16x32_f16; weights in registers; h published per step to
//   double-buffered LDS as f16 hi + f16 lo (split-float ~fp32 recurrence).
// Wave 7: output head for h_{t-1}: 4 vocab tiles (hi+lo), intra-wave
//   log_softmax, scattered-but-64B-coalesced dword stores.
//
// v4 changes (x-latency + LDS-pipe attack):
//  * 2-step-deep x prefetch: ping-pong register buffers hold x(t+1) and
//    x(t+2); loads are in flight ~2 full steps (>> ~900cy HBM latency), so
//    the per-step vmcnt wait at the convert point is ~free. (v3 exposed
//    ~600+cy of HBM latency every step on 7 of 8 waves.)
//  * softmax reductions via DPP (VALU pipe: quad_perm xor1/xor2 +
//    row_half_mirror + row_mirror) instead of __shfl_xor (chained LDS-pipe
//    ds_bpermute) -- removes ~350cy chain from the head wave and 32 ds ops
//    per step from the LDS pipe that every wave drains at lgkmcnt(0).

#define T_STEPS 512
#define BATCH   1024
#define VOCAB   64
#define HID     100
#define BB      16      // batch rows per block (MFMA M)
#define NKH     4       // h k-steps (K=128 padded; k==100 is bias column)
#define NKX     2       // x k-steps (K=64)
#define HSTR    136     // f16 row stride for h fragment buffers

typedef _Float16 f16;
typedef _Float16 f16x8 __attribute__((ext_vector_type(8)));
typedef float    f32x4 __attribute__((ext_vector_type(4)));

#define MFMA(A_, B_, C_) __builtin_amdgcn_mfma_f32_16x16x32_f16((A_), (B_), (C_), 0, 0, 0)

__device__ __forceinline__ float rcp_f(float v)  { return __builtin_amdgcn_rcpf(v); }
__device__ __forceinline__ float sigm(float v)   { return rcp_f(1.0f + __expf(-v)); }
__device__ __forceinline__ float tanh_f(float v) { return 1.0f - 2.0f * rcp_f(__expf(2.0f * v) + 1.0f); }

// DPP lane move within the 16-lane row (VALU pipe, ~2cy; replaces ds_bpermute).
template<int CTRL>
__device__ __forceinline__ float dpp_mov(float v) {
    return __int_as_float(__builtin_amdgcn_update_dpp(
        0, __float_as_int(v), CTRL, 0xF, 0xF, true));
}
// All-reduce over each 16-lane group: quad xor1 (0xB1), quad xor2 (0x4E),
// row_half_mirror (0x141), row_mirror (0x140).
__device__ __forceinline__ float red_max16(float v) {
    v = fmaxf(v, dpp_mov<0xB1>(v));
    v = fmaxf(v, dpp_mov<0x4E>(v));
    v = fmaxf(v, dpp_mov<0x141>(v));
    v = fmaxf(v, dpp_mov<0x140>(v));
    return v;
}
__device__ __forceinline__ float red_sum16(float v) {
    v += dpp_mov<0xB1>(v);
    v += dpp_mov<0x4E>(v);
    v += dpp_mov<0x141>(v);
    v += dpp_mov<0x140>(v);
    return v;
}

// Barrier that only orders LDS: no vmcnt(0) drain (global stores/loads stay
// in flight across the step boundary; only LDS has cross-wave deps).
__device__ __forceinline__ void sync_lds() {
    __builtin_amdgcn_sched_barrier(0);
    asm volatile("s_waitcnt lgkmcnt(0)" ::: "memory");
    __builtin_amdgcn_s_barrier();
    __builtin_amdgcn_sched_barrier(0);
}

#define XPTR(tt) (x + ((size_t)(tt) * BATCH + rowbase + c) * VOCAB + lg * 8)
#define LOADX(P0, P1, P2, P3, tt) do {                         \
    const float* xp_ = XPTR(tt);                               \
    P0 = *reinterpret_cast<const float4*>(xp_);                \
    P1 = *reinterpret_cast<const float4*>(xp_ + 4);            \
    P2 = *reinterpret_cast<const float4*>(xp_ + 32);           \
    P3 = *reinterpret_cast<const float4*>(xp_ + 36);           \
} while (0)
#define CVTX(P0, P1, P2, P3) do {                                          \
    f16x8 v_;                                                              \
    v_[0]=(f16)P0.x; v_[1]=(f16)P0.y; v_[2]=(f16)P0.z; v_[3]=(f16)P0.w;    \
    v_[4]=(f16)P1.x; v_[5]=(f16)P1.y; v_[6]=(f16)P1.z; v_[7]=(f16)P1.w;    \
    xf[0] = v_;                                                            \
    v_[0]=(f16)P2.x; v_[1]=(f16)P2.y; v_[2]=(f16)P2.z; v_[3]=(f16)P2.w;    \
    v_[4]=(f16)P3.x; v_[5]=(f16)P3.y; v_[6]=(f16)P3.z; v_[7]=(f16)P3.w;    \
    xf[1] = v_;                                                            \
} while (0)

__global__ __launch_bounds__(512, 2) void gru_mfma(
    const float* __restrict__ x, const float* __restrict__ h0,
    const int* __restrict__ lengths,
    const float* __restrict__ W_ih, const float* __restrict__ W_hh,
    const float* __restrict__ b_ih, const float* __restrict__ b_hh,
    const float* __restrict__ W_out, const float* __restrict__ b_out,
    float* __restrict__ out)
{
    const int tid = threadIdx.x;
    const int w   = tid >> 6;        // wave 0..7
    const int l   = tid & 63;
    const int c   = l & 15;          // frag col (A batch-row / B gate or vocab col)
    const int lg  = l >> 4;          // lane group 0..3
    const int rowbase = blockIdx.x * BB;

    __shared__ alignas(16) f16 hHi[2][BB * HSTR];
    __shared__ alignas(16) f16 hLo[2][BB * HSTR];

    // Union'd weight fragments:
    //   waves 0..6: wf[s*4+ks] = W_hh^T frags (s=r/z/n; +bias col k=100)
    //               wf[12+s*2+ks] = W_ih^T frags
    //   wave 7:     wf[v*4+ks] = W_out^T frags for vocab tile v (+b_out col)
    f16x8 wf[18];
    float bin = 0.f;        // b_ih(n) for this lane's gate col
    float hold4[4];         // fp32 hidden owned by this thread (rows lg*4+r)
    int   lenv[4];

    #pragma unroll
    for (int r = 0; r < 4; ++r) lenv[r] = lengths[rowbase + lg * 4 + r];

    if (w < 7) {
        const int gl = 16 * w + c;
        const bool gv = gl < HID;
        #pragma unroll
        for (int s = 0; s < 3; ++s) {
            const int g = s * HID + gl;
            #pragma unroll
            for (int ks = 0; ks < NKH; ++ks) {
                f16x8 v;
                #pragma unroll
                for (int j = 0; j < 8; ++j) {
                    const int k = ks * 32 + lg * 8 + j;
                    float val = 0.f;
                    if (gv) {
                        if (k < HID)        val = W_hh[(size_t)g * HID + k];
                        else if (k == HID)  val = (s < 2) ? (b_ih[g] + b_hh[g]) : b_hh[g];
                    }
                    v[j] = (f16)val;
                }
                wf[s * 4 + ks] = v;
            }
            #pragma unroll
            for (int ks = 0; ks < NKX; ++ks) {
                f16x8 v;
                #pragma unroll
                for (int j = 0; j < 8; ++j) {
                    const int k = ks * 32 + lg * 8 + j;
                    v[j] = (f16)(gv ? W_ih[(size_t)g * VOCAB + k] : 0.f);
                }
                wf[12 + s * 2 + ks] = v;
            }
        }
        bin = gv ? b_ih[2 * HID + gl] : 0.f;

        // initial hidden: fp32 regs + hi/lo frags into buffer 0
        #pragma unroll
        for (int r = 0; r < 4; ++r) {
            const int row = lg * 4 + r;
            float hv = gv ? h0[(size_t)(rowbase + row) * HID + gl] : 0.f;
            hold4[r] = hv;
            if (gv) {
                f16 hi = (f16)hv;
                hHi[0][row * HSTR + gl] = hi;
                hLo[0][row * HSTR + gl] = (f16)(hv - (float)hi);
            }
        }
    } else {
        #pragma unroll
        for (int vt = 0; vt < 4; ++vt) {
            const int vr = 16 * vt + c;      // vocab row of W_out
            #pragma unroll
            for (int ks = 0; ks < NKH; ++ks) {
                f16x8 v;
                #pragma unroll
                for (int j = 0; j < 8; ++j) {
                    const int k = ks * 32 + lg * 8 + j;
                    float val = 0.f;
                    if (k < HID)        val = W_out[(size_t)vr * HID + k];
                    else if (k == HID)  val = b_out[vr];
                    v[j] = (f16)val;
                }
                wf[vt * 4 + ks] = v;
            }
        }
        hold4[0] = hold4[1] = hold4[2] = hold4[3] = 0.f;
    }

    if (tid < BB) {
        #pragma unroll
        for (int k = HID; k < 128; ++k) {
            hHi[0][tid * HSTR + k] = (f16)0.f;  hLo[0][tid * HSTR + k] = (f16)0.f;
            hHi[1][tid * HSTR + k] = (f16)0.f;  hLo[1][tid * HSTR + k] = (f16)0.f;
        }
        hHi[0][tid * HSTR + HID] = (f16)1.0f;   // bias column (both buffers)
        hHi[1][tid * HSTR + HID] = (f16)1.0f;
    }

    // x pipeline state (gate waves): xf = frags for step t;
    // pA/pB = raw float4 of x(t+1)/x(t+2), ~2 steps in flight.
    f16x8  xf[2];
    float4 pA0, pA1, pA2, pA3, pB0, pB1, pB2, pB3;
    if (w < 7) {
        LOADX(pA0, pA1, pA2, pA3, 0);
        CVTX(pA0, pA1, pA2, pA3);            // xf = x(0)
        LOADX(pA0, pA1, pA2, pA3, 1);        // pA = x(1), in flight
        LOADX(pB0, pB1, pB2, pB3, 2);        // pB = x(2), in flight
    }
    __syncthreads();   // prologue: full barrier once is fine

    // Loop runs one extra iteration: gate waves act for t<T, head wave for t>0.
    for (int t = 0; t <= T_STEPS; ++t) {
        const int cur = t & 1;               // buf[cur] holds h_{t-1}
        if (w < 7) {
            if (t < T_STEPS) {
                // h fragments
                f16x8 hh[NKH], hl[NKH];
                #pragma unroll
                for (int ks = 0; ks < NKH; ++ks) {
                    const int off = c * HSTR + ks * 32 + lg * 8;
                    hh[ks] = *reinterpret_cast<const f16x8*>(&hHi[cur][off]);
                    hl[ks] = *reinterpret_cast<const f16x8*>(&hLo[cur][off]);
                }

                // split accumulators: x->hi chain (depth 6) || lo chain (depth 4)
                f32x4 zz = {0.f, 0.f, 0.f, 0.f};
                f32x4 aRa = zz, aZa = zz, aNX = zz;
                f32x4 aRb = zz, aZb = zz, aNHa = zz, aNHb = zz;
                #pragma unroll
                for (int ks = 0; ks < NKX; ++ks) {
                    aRa = MFMA(xf[ks], wf[12 + ks], aRa);
                    aZa = MFMA(xf[ks], wf[14 + ks], aZa);
                    aNX = MFMA(xf[ks], wf[16 + ks], aNX);
                }
                #pragma unroll
                for (int ks = 0; ks < NKH; ++ks) {
                    aRa  = MFMA(hh[ks], wf[0 + ks], aRa);
                    aRb  = MFMA(hl[ks], wf[0 + ks], aRb);
                    aZa  = MFMA(hh[ks], wf[4 + ks], aZa);
                    aZb  = MFMA(hl[ks], wf[4 + ks], aZb);
                    aNHa = MFMA(hh[ks], wf[8 + ks], aNHa);
                    aNHb = MFMA(hl[ks], wf[8 + ks], aNHb);
                }

                // x pipeline: convert x(t+1) (loaded ~2 steps ago -> vmcnt wait
                // is ~free), then refill the slot with x(t+3).
                if ((t & 1) == 0) {
                    CVTX(pA0, pA1, pA2, pA3);
                    const int tt = (t + 3 < T_STEPS) ? t + 3 : T_STEPS - 1;
                    LOADX(pA0, pA1, pA2, pA3, tt);
                } else {
                    CVTX(pB0, pB1, pB2, pB3);
                    const int tt = (t + 3 < T_STEPS) ? t + 3 : T_STEPS - 1;
                    LOADX(pB0, pB1, pB2, pB3, tt);
                }

                // pointwise + publish h_t into buf[cur^1]
                const int kk = 16 * w + c;
                const bool kv = kk < HID;
                #pragma unroll
                for (int r = 0; r < 4; ++r) {
                    float rg   = sigm(aRa[r] + aRb[r]);
                    float zg   = sigm(aZa[r] + aZb[r]);
                    float ng   = tanh_f(fmaf(rg, aNHa[r] + aNHb[r], aNX[r] + bin));
                    float hnew = fmaf(zg, hold4[r] - ng, ng);   // (1-z)n + z*h
                    float hv   = (t < lenv[r]) ? hnew : hold4[r];
                    hold4[r] = hv;
                    if (kv) {
                        const int row = lg * 4 + r;
                        f16 hi = (f16)hv;
                        hHi[cur ^ 1][row * HSTR + kk] = hi;
                        hLo[cur ^ 1][row * HSTR + kk] = (f16)(hv - (float)hi);
                    }
                }
            }
        } else {
            if (t > 0) {
                // head over h_{t-1} (buf[cur]) -> output row t-1
                const int tp = t - 1;
                f16x8 hh[NKH], hl[NKH];
                #pragma unroll
                for (int ks = 0; ks < NKH; ++ks) {
                    const int off = c * HSTR + ks * 32 + lg * 8;
                    hh[ks] = *reinterpret_cast<const f16x8*>(&hHi[cur][off]);
                    hl[ks] = *reinterpret_cast<const f16x8*>(&hLo[cur][off]);
                }
                f32x4 zz = {0.f, 0.f, 0.f, 0.f};
                f32x4 a0h = zz, a1h = zz, a2h = zz, a3h = zz;
                f32x4 a0l = zz, a1l = zz, a2l = zz, a3l = zz;
                #pragma unroll
                for (int ks = 0; ks < NKH; ++ks) {
                    a0h = MFMA(hh[ks], wf[0  + ks], a0h);
                    a0l = MFMA(hl[ks], wf[0  + ks], a0l);
                    a1h = MFMA(hh[ks], wf[4  + ks], a1h);
                    a1l = MFMA(hl[ks], wf[4  + ks], a1l);
                    a2h = MFMA(hh[ks], wf[8  + ks], a2h);
                    a2l = MFMA(hl[ks], wf[8  + ks], a2l);
                    a3h = MFMA(hh[ks], wf[12 + ks], a3h);
                    a3l = MFMA(hl[ks], wf[12 + ks], a3l);
                }
                // intra-wave log_softmax per row (DPP all-reduce over 16-lane
                // groups, VALU pipe); scattered 64B-coalesced dword stores
                // (never drained at the barrier).
                #pragma unroll
                for (int r = 0; r < 4; ++r) {
                    float v0 = a0h[r] + a0l[r];
                    float v1 = a1h[r] + a1l[r];
                    float v2 = a2h[r] + a2l[r];
                    float v3 = a3h[r] + a3l[r];
                    float m = red_max16(fmaxf(fmaxf(v0, v1), fmaxf(v2, v3)));
                    float s = red_sum16(__expf(v0 - m) + __expf(v1 - m)
                                      + __expf(v2 - m) + __expf(v3 - m));
                    float ls = m + __logf(s);
                    const bool act = tp < lenv[r];
                    float* orow = out + ((size_t)tp * BATCH + rowbase + lg * 4 + r) * VOCAB + c;
                    orow[ 0] = act ? (v0 - ls) : 0.f;
                    orow[16] = act ? (v1 - ls) : 0.f;
                    orow[32] = act ? (v2 - ls) : 0.f;
                    orow[48] = act ? (v3 - ls) : 0.f;
                }
            }
        }
        sync_lds();
    }
}

extern "C" void kernel_launch(void* const* d_in, const int* in_sizes, int n_in,
                              void* d_out, int out_size, void* d_ws, size_t ws_size,
                              hipStream_t stream) {
    const float* x     = (const float*)d_in[0];
    const float* h0    = (const float*)d_in[1];
    const int*   lens  = (const int*)  d_in[2];
    const float* W_ih  = (const float*)d_in[3];
    const float* W_hh  = (const float*)d_in[4];
    const float* b_ih  = (const float*)d_in[5];
    const float* b_hh  = (const float*)d_in[6];
    const float* W_out = (const float*)d_in[7];
    const float* b_out = (const float*)d_in[8];
    float* outp = (float*)d_out;

    gru_mfma<<<BATCH / BB, 512, 0, stream>>>(x, h0, lens, W_ih, W_hh,
                                             b_ih, b_hh, W_out, b_out, outp);
}

// Round 6
// 903.900 us; speedup vs baseline: 1.2908x; 1.2908x over previous
//
#include <hip/hip_runtime.h>

// Packed-sequence GRU decoder + fused log_softmax head, MFMA formulation, v5
// (resubmission -- round-5 bench failed on infra, no kernel signal).
// T=512, B=1024, V=64, H=100.
//
// 64 blocks x 512 threads (8 waves); block owns 16 batch rows (one MFMA M-tile).
// Waves 0..6: gate tile w (16 gate cols x 3 sections r/z/n) via
//   mfma_f32_16x16x32_f16; weights in registers; h published per step to
//   double-buffered LDS as f16 hi + f16 lo (split-float ~fp32 recurrence).
// Wave 7: (a) x-stager: loads x(t+1) f32 (2-step-deep reg pipeline), converts
//   to f16 fragments in double-buffered LDS -- gate waves no longer touch x
//   (kills the 7x-redundant load+convert that was ~45% of all VALU cycles);
//   (b) output head for h_{t-1} from the f16 HI fragments only (precision
//   validated by the round-0 kernel), 16 MFMAs, DPP log_softmax, coalesced
//   stores.
// ONE lgkm-only barrier per step (global loads/stores never drained).
// s_setprio(1) wraps the gate-wave MFMA cluster (wave role diversity now
// exists for the CU scheduler to arbitrate).

#define T_STEPS 512
#define BATCH   1024
#define VOCAB   64
#define HID     100
#define BB      16      // batch rows per block (MFMA M)
#define NKH     4       // h k-steps (K=128 padded; k==100 is bias column)
#define HSTR    136     // f16 row stride for h fragment buffers
#define XSTR    72      // f16 row stride for x fragment buffer (16B-aligned)

typedef _Float16 f16;
typedef _Float16 f16x8 __attribute__((ext_vector_type(8)));
typedef float    f32x4 __attribute__((ext_vector_type(4)));

#define MFMA(A_, B_, C_) __builtin_amdgcn_mfma_f32_16x16x32_f16((A_), (B_), (C_), 0, 0, 0)

__device__ __forceinline__ float rcp_f(float v)  { return __builtin_amdgcn_rcpf(v); }
__device__ __forceinline__ float sigm(float v)   { return rcp_f(1.0f + __expf(-v)); }
__device__ __forceinline__ float tanh_f(float v) { return 1.0f - 2.0f * rcp_f(__expf(2.0f * v) + 1.0f); }

// DPP lane move within the 16-lane row (VALU pipe; replaces ds_bpermute).
template<int CTRL>
__device__ __forceinline__ float dpp_mov(float v) {
    return __int_as_float(__builtin_amdgcn_update_dpp(
        0, __float_as_int(v), CTRL, 0xF, 0xF, true));
}
__device__ __forceinline__ float red_max16(float v) {
    v = fmaxf(v, dpp_mov<0xB1>(v));
    v = fmaxf(v, dpp_mov<0x4E>(v));
    v = fmaxf(v, dpp_mov<0x141>(v));
    v = fmaxf(v, dpp_mov<0x140>(v));
    return v;
}
__device__ __forceinline__ float red_sum16(float v) {
    v += dpp_mov<0xB1>(v);
    v += dpp_mov<0x4E>(v);
    v += dpp_mov<0x141>(v);
    v += dpp_mov<0x140>(v);
    return v;
}

// Barrier that only orders LDS: no vmcnt(0) drain.
__device__ __forceinline__ void sync_lds() {
    __builtin_amdgcn_sched_barrier(0);
    asm volatile("s_waitcnt lgkmcnt(0)" ::: "memory");
    __builtin_amdgcn_s_barrier();
    __builtin_amdgcn_sched_barrier(0);
}

// Head-wave x staging: lane l covers batch-row (l>>2), cols (l&3)*16..+15.
#define HLOADX(P0, P1, P2, P3, tt) do {                                     \
    const float* xp_ = x + ((size_t)(tt) * BATCH + rowbase + xrow) * VOCAB + xcol; \
    P0 = *reinterpret_cast<const float4*>(xp_);                             \
    P1 = *reinterpret_cast<const float4*>(xp_ + 4);                         \
    P2 = *reinterpret_cast<const float4*>(xp_ + 8);                         \
    P3 = *reinterpret_cast<const float4*>(xp_ + 12);                        \
} while (0)
#define HSTAGEX(P0, P1, P2, P3, buf) do {                                   \
    f16x8 a_, b_;                                                           \
    a_[0]=(f16)P0.x; a_[1]=(f16)P0.y; a_[2]=(f16)P0.z; a_[3]=(f16)P0.w;     \
    a_[4]=(f16)P1.x; a_[5]=(f16)P1.y; a_[6]=(f16)P1.z; a_[7]=(f16)P1.w;     \
    b_[0]=(f16)P2.x; b_[1]=(f16)P2.y; b_[2]=(f16)P2.z; b_[3]=(f16)P2.w;     \
    b_[4]=(f16)P3.x; b_[5]=(f16)P3.y; b_[6]=(f16)P3.z; b_[7]=(f16)P3.w;     \
    *reinterpret_cast<f16x8*>(&xs[buf][xrow][xcol])     = a_;               \
    *reinterpret_cast<f16x8*>(&xs[buf][xrow][xcol + 8]) = b_;               \
} while (0)

__global__ __launch_bounds__(512, 2) void gru_mfma(
    const float* __restrict__ x, const float* __restrict__ h0,
    const int* __restrict__ lengths,
    const float* __restrict__ W_ih, const float* __restrict__ W_hh,
    const float* __restrict__ b_ih, const float* __restrict__ b_hh,
    const float* __restrict__ W_out, const float* __restrict__ b_out,
    float* __restrict__ out)
{
    const int tid = threadIdx.x;
    const int w   = tid >> 6;        // wave 0..7
    const int l   = tid & 63;
    const int c   = l & 15;          // frag col (A batch-row / B gate or vocab col)
    const int lg  = l >> 4;          // lane group 0..3
    const int rowbase = blockIdx.x * BB;

    __shared__ alignas(16) f16 hHi[2][BB * HSTR];
    __shared__ alignas(16) f16 hLo[2][BB * HSTR];
    __shared__ alignas(16) f16 xs[2][BB][XSTR];   // x_t fragments (f16)

    // Union'd weight fragments:
    //   waves 0..6: wf[s*4+ks]   = W_hh^T frags (s=r/z/n; +bias col k=100)
    //               wf[12+s*2+ks]= W_ih^T frags
    //   wave 7:     wf[v*4+ks]   = W_out^T frags for vocab tile v (+b_out col)
    f16x8 wf[18];
    float bin = 0.f;        // b_ih(n) for this lane's gate col
    float hold4[4];         // fp32 hidden owned by this thread (rows lg*4+r)
    int   lenv[4];

    #pragma unroll
    for (int r = 0; r < 4; ++r) lenv[r] = lengths[rowbase + lg * 4 + r];

    if (w < 7) {
        const int gl = 16 * w + c;
        const bool gv = gl < HID;
        #pragma unroll
        for (int s = 0; s < 3; ++s) {
            const int g = s * HID + gl;
            #pragma unroll
            for (int ks = 0; ks < NKH; ++ks) {
                f16x8 v;
                #pragma unroll
                for (int j = 0; j < 8; ++j) {
                    const int k = ks * 32 + lg * 8 + j;
                    float val = 0.f;
                    if (gv) {
                        if (k < HID)        val = W_hh[(size_t)g * HID + k];
                        else if (k == HID)  val = (s < 2) ? (b_ih[g] + b_hh[g]) : b_hh[g];
                    }
                    v[j] = (f16)val;
                }
                wf[s * 4 + ks] = v;
            }
            #pragma unroll
            for (int ks = 0; ks < 2; ++ks) {
                f16x8 v;
                #pragma unroll
                for (int j = 0; j < 8; ++j) {
                    const int k = ks * 32 + lg * 8 + j;
                    v[j] = (f16)(gv ? W_ih[(size_t)g * VOCAB + k] : 0.f);
                }
                wf[12 + s * 2 + ks] = v;
            }
        }
        bin = gv ? b_ih[2 * HID + gl] : 0.f;

        // initial hidden: fp32 regs + hi/lo frags into buffer 0
        #pragma unroll
        for (int r = 0; r < 4; ++r) {
            const int row = lg * 4 + r;
            float hv = gv ? h0[(size_t)(rowbase + row) * HID + gl] : 0.f;
            hold4[r] = hv;
            if (gv) {
                f16 hi = (f16)hv;
                hHi[0][row * HSTR + gl] = hi;
                hLo[0][row * HSTR + gl] = (f16)(hv - (float)hi);
            }
        }
    } else {
        #pragma unroll
        for (int vt = 0; vt < 4; ++vt) {
            const int vr = 16 * vt + c;      // vocab row of W_out
            #pragma unroll
            for (int ks = 0; ks < NKH; ++ks) {
                f16x8 v;
                #pragma unroll
                for (int j = 0; j < 8; ++j) {
                    const int k = ks * 32 + lg * 8 + j;
                    float val = 0.f;
                    if (k < HID)        val = W_out[(size_t)vr * HID + k];
                    else if (k == HID)  val = b_out[vr];
                    v[j] = (f16)val;
                }
                wf[vt * 4 + ks] = v;
            }
        }
        hold4[0] = hold4[1] = hold4[2] = hold4[3] = 0.f;
    }

    if (tid < BB) {
        #pragma unroll
        for (int k = HID; k < 128; ++k) {
            hHi[0][tid * HSTR + k] = (f16)0.f;  hLo[0][tid * HSTR + k] = (f16)0.f;
            hHi[1][tid * HSTR + k] = (f16)0.f;  hLo[1][tid * HSTR + k] = (f16)0.f;
        }
        hHi[0][tid * HSTR + HID] = (f16)1.0f;   // bias column (both buffers)
        hHi[1][tid * HSTR + HID] = (f16)1.0f;
    }

    // Head-wave x pipeline: qA = x(t+1) on even t, qB = x(t+2) -- ~2 steps
    // of HBM latency in flight.
    const int xrow = l >> 2;
    const int xcol = (l & 3) * 16;
    float4 qA0, qA1, qA2, qA3, qB0, qB1, qB2, qB3;
    if (w == 7) {
        HLOADX(qA0, qA1, qA2, qA3, 0);
        HSTAGEX(qA0, qA1, qA2, qA3, 0);      // xs[0] = x(0)
        HLOADX(qA0, qA1, qA2, qA3, 1);       // in flight
        HLOADX(qB0, qB1, qB2, qB3, 2);       // in flight
    }
    __syncthreads();   // prologue: full barrier once is fine

    // Loop runs one extra iteration: gate waves act for t<T, head for t>0.
    for (int t = 0; t <= T_STEPS; ++t) {
        const int cur = t & 1;               // buf[cur] holds h_{t-1}
        if (w < 7) {
            if (t < T_STEPS) {
                // x fragments from LDS (staged by head wave last step)
                f16x8 xq0 = *reinterpret_cast<const f16x8*>(&xs[cur][c][lg * 8]);
                f16x8 xq1 = *reinterpret_cast<const f16x8*>(&xs[cur][c][32 + lg * 8]);
                // h fragments
                f16x8 hh[NKH], hl[NKH];
                #pragma unroll
                for (int ks = 0; ks < NKH; ++ks) {
                    const int off = c * HSTR + ks * 32 + lg * 8;
                    hh[ks] = *reinterpret_cast<const f16x8*>(&hHi[cur][off]);
                    hl[ks] = *reinterpret_cast<const f16x8*>(&hLo[cur][off]);
                }

                f32x4 zz = {0.f, 0.f, 0.f, 0.f};
                f32x4 aRa = zz, aZa = zz, aNX = zz;
                f32x4 aRb = zz, aZb = zz, aNHa = zz, aNHb = zz;
                __builtin_amdgcn_s_setprio(1);
                aRa = MFMA(xq0, wf[12], aRa);
                aZa = MFMA(xq0, wf[14], aZa);
                aNX = MFMA(xq0, wf[16], aNX);
                aRa = MFMA(xq1, wf[13], aRa);
                aZa = MFMA(xq1, wf[15], aZa);
                aNX = MFMA(xq1, wf[17], aNX);
                #pragma unroll
                for (int ks = 0; ks < NKH; ++ks) {
                    aRa  = MFMA(hh[ks], wf[0 + ks], aRa);
                    aRb  = MFMA(hl[ks], wf[0 + ks], aRb);
                    aZa  = MFMA(hh[ks], wf[4 + ks], aZa);
                    aZb  = MFMA(hl[ks], wf[4 + ks], aZb);
                    aNHa = MFMA(hh[ks], wf[8 + ks], aNHa);
                    aNHb = MFMA(hl[ks], wf[8 + ks], aNHb);
                }
                __builtin_amdgcn_s_setprio(0);

                // pointwise + publish h_t into buf[cur^1]
                const int kk = 16 * w + c;
                const bool kv = kk < HID;
                #pragma unroll
                for (int r = 0; r < 4; ++r) {
                    float rg   = sigm(aRa[r] + aRb[r]);
                    float zg   = sigm(aZa[r] + aZb[r]);
                    float ng   = tanh_f(fmaf(rg, aNHa[r] + aNHb[r], aNX[r] + bin));
                    float hnew = fmaf(zg, hold4[r] - ng, ng);   // (1-z)n + z*h
                    float hv   = (t < lenv[r]) ? hnew : hold4[r];
                    hold4[r] = hv;
                    if (kv) {
                        const int row = lg * 4 + r;
                        f16 hi = (f16)hv;
                        hHi[cur ^ 1][row * HSTR + kk] = hi;
                        hLo[cur ^ 1][row * HSTR + kk] = (f16)(hv - (float)hi);
                    }
                }
            }
        } else {
            // (a) stage x(t+1) into xs[(t+1)&1]; refill the reg slot with x(t+3)
            if (t < T_STEPS) {
                const int tt = (t + 3 < T_STEPS) ? t + 3 : T_STEPS - 1;
                if ((t & 1) == 0) {
                    HSTAGEX(qA0, qA1, qA2, qA3, 1);
                    HLOADX(qA0, qA1, qA2, qA3, tt);
                } else {
                    HSTAGEX(qB0, qB1, qB2, qB3, 0);
                    HLOADX(qB0, qB1, qB2, qB3, tt);
                }
            }
            // (b) head over h_{t-1} (HI fragments only) -> output row t-1
            if (t > 0) {
                const int tp = t - 1;
                f16x8 hh[NKH];
                #pragma unroll
                for (int ks = 0; ks < NKH; ++ks) {
                    const int off = c * HSTR + ks * 32 + lg * 8;
                    hh[ks] = *reinterpret_cast<const f16x8*>(&hHi[cur][off]);
                }
                f32x4 zz = {0.f, 0.f, 0.f, 0.f};
                f32x4 a0 = zz, a1 = zz, a2 = zz, a3 = zz;
                #pragma unroll
                for (int ks = 0; ks < NKH; ++ks) {
                    a0 = MFMA(hh[ks], wf[0  + ks], a0);
                    a1 = MFMA(hh[ks], wf[4  + ks], a1);
                    a2 = MFMA(hh[ks], wf[8  + ks], a2);
                    a3 = MFMA(hh[ks], wf[12 + ks], a3);
                }
                #pragma unroll
                for (int r = 0; r < 4; ++r) {
                    float v0 = a0[r], v1 = a1[r], v2 = a2[r], v3 = a3[r];
                    float m = red_max16(fmaxf(fmaxf(v0, v1), fmaxf(v2, v3)));
                    float s = red_sum16(__expf(v0 - m) + __expf(v1 - m)
                                      + __expf(v2 - m) + __expf(v3 - m));
                    float ls = m + __logf(s);
                    const bool act = tp < lenv[r];
                    float* orow = out + ((size_t)tp * BATCH + rowbase + lg * 4 + r) * VOCAB + c;
                    orow[ 0] = act ? (v0 - ls) : 0.f;
                    orow[16] = act ? (v1 - ls) : 0.f;
                    orow[32] = act ? (v2 - ls) : 0.f;
                    orow[48] = act ? (v3 - ls) : 0.f;
                }
            }
        }
        sync_lds();
    }
}

extern "C" void kernel_launch(void* const* d_in, const int* in_sizes, int n_in,
                              void* d_out, int out_size, void* d_ws, size_t ws_size,
                              hipStream_t stream) {
    const float* x     = (const float*)d_in[0];
    const float* h0    = (const float*)d_in[1];
    const int*   lens  = (const int*)  d_in[2];
    const float* W_ih  = (const float*)d_in[3];
    const float* W_hh  = (const float*)d_in[4];
    const float* b_ih  = (const float*)d_in[5];
    const float* b_hh  = (const float*)d_in[6];
    const float* W_out = (const float*)d_in[7];
    const float* b_out = (const float*)d_in[8];
    float* outp = (float*)d_out;

    gru_mfma<<<BATCH / BB, 512, 0, stream>>>(x, h0, lens, W_ih, W_hh,
                                             b_ih, b_hh, W_out, b_out, outp);
}